// Round 1
// baseline (380.625 us; speedup 1.0000x reference)
//
#include <hip/hip_runtime.h>
#include <hip/hip_bf16.h>
#include <stdint.h>

// ---------------------------------------------------------------------------
// SelectiveMixing: x->W1->silu->W2->(q,k,g); v=(x@Wv+bv)*sig(g);
// attn=softmax(qk^T/sqrt(D)); out=rmsnorm(mix*attn@v + (1-mix)*x)
// B=4, L=2048, D=1024, INNER=1536. All matmuls in bf16 MFMA, f32 accum.
// ---------------------------------------------------------------------------

typedef __bf16 bf16x8 __attribute__((ext_vector_type(8)));
typedef float f32x4 __attribute__((ext_vector_type(4)));

__device__ __forceinline__ unsigned short f2bf(float f) {
    unsigned int u = __float_as_uint(f);
    u += 0x7fffu + ((u >> 16) & 1u);
    return (unsigned short)(u >> 16);
}
__device__ __forceinline__ float bf2f(unsigned short s) {
    return __uint_as_float(((unsigned int)s) << 16);
}
__device__ __forceinline__ void llds16(const void* g, void* l) {
    __builtin_amdgcn_global_load_lds(
        (const __attribute__((address_space(1))) void*)g,
        (__attribute__((address_space(3))) void*)l, 16, 0, 0);
}

// ---------------- elementwise: f32 -> bf16 (8 elems/thread) ----------------
__global__ __launch_bounds__(256) void cvt_f32_bf16(
    const float* __restrict__ in, unsigned short* __restrict__ out, long long n8) {
    long long i = (long long)blockIdx.x * 256 + threadIdx.x;
    if (i >= n8) return;
    float4 a = ((const float4*)in)[2 * i];
    float4 b = ((const float4*)in)[2 * i + 1];
    ushort4 p0, p1;
    p0.x = f2bf(a.x); p0.y = f2bf(a.y); p0.z = f2bf(a.z); p0.w = f2bf(a.w);
    p1.x = f2bf(b.x); p1.y = f2bf(b.y); p1.z = f2bf(b.z); p1.w = f2bf(b.w);
    ((ushort4*)out)[2 * i] = p0;
    ((ushort4*)out)[2 * i + 1] = p1;
}

// ---------------- transpose + convert: f32 [R][C] -> bf16 [C][R] -----------
__global__ __launch_bounds__(256) void transpose_cvt(
    const float* __restrict__ in, unsigned short* __restrict__ out, int R, int C) {
    __shared__ unsigned short tile[32][33];
    int c0 = blockIdx.x * 32, r0 = blockIdx.y * 32;
    int cc = threadIdx.x & 31, rr = threadIdx.x >> 5;  // 32 cols x 8 rows per pass
#pragma unroll
    for (int p = 0; p < 4; ++p) {
        int r = rr + p * 8;
        tile[r][cc] = f2bf(in[(size_t)(r0 + r) * C + c0 + cc]);
    }
    __syncthreads();
#pragma unroll
    for (int p = 0; p < 4; ++p) {
        int c = rr + p * 8;  // output row = original column
        out[(size_t)(c0 + c) * R + r0 + cc] = tile[cc][c];
    }
}

// ---------------- generic bf16 GEMM, C = A @ B^T, templated epilogue -------
// A: [M][K] bf16 (row-major, lda), B: [N][K] bf16 (row-major, ldb)
// EPI 0: out bf16 = silu(acc + bias[n])
// EPI 1: out bf16 = acc + bias[n]
// EPI 2: vT bf16: out[(m>>11)*D + n][m&2047] = (acc+bias[n])*sigmoid(gate[m*ldg+n])
// EPI 3: out f32 = acc * scale            (scores)
// EPI 4: out f32 = mix[n]*acc + (1-mix[n])*xres[m*ldo+n]   (PV + residual mix)
template <int EPI>
__global__ __launch_bounds__(256) void gemm_bt(
    const unsigned short* __restrict__ A, int lda, long long Abs,
    const unsigned short* __restrict__ B, int ldb, long long Bbs,
    int K,
    void* __restrict__ out, int ldo, long long Obs,
    const float* __restrict__ bias,
    const unsigned short* __restrict__ gate, int ldg,
    const float* __restrict__ xres, const float* __restrict__ mix,
    float scale) {
    __shared__ unsigned short Alds[128 * 32];
    __shared__ unsigned short Blds[128 * 32];
    const int tid = threadIdx.x;
    const int lane = tid & 63, wid = tid >> 6;
    const int wr = wid >> 1, wc = wid & 1;  // 2x2 waves, 64x64 each
    const int bm = blockIdx.y * 128, bn = blockIdx.x * 128;
    const int z = blockIdx.z;
    A += (long long)z * Abs;
    B += (long long)z * Bbs;

    f32x4 acc[4][4] = {};

    const int sr = lane >> 2;        // row within 16-row chunk
    const int sk = (lane & 3) * 8;   // k offset (8 bf16 = 16B)

    for (int k0 = 0; k0 < K; k0 += 32) {
        __syncthreads();
#pragma unroll
        for (int it = 0; it < 2; ++it) {
            int chunk = wid + 4 * it;  // 0..7, each = 16 rows x 32 k
            int r = chunk * 16 + sr;
            llds16(A + (size_t)(bm + r) * lda + k0 + sk, &Alds[chunk * 512]);
            llds16(B + (size_t)(bn + r) * ldb + k0 + sk, &Blds[chunk * 512]);
        }
        __syncthreads();
        bf16x8 af[4], bfr[4];
#pragma unroll
        for (int i = 0; i < 4; ++i) {
            int arow = wr * 64 + i * 16 + (lane & 15);
            af[i] = *(const bf16x8*)&Alds[arow * 32 + (lane >> 4) * 8];
            int brow = wc * 64 + i * 16 + (lane & 15);
            bfr[i] = *(const bf16x8*)&Blds[brow * 32 + (lane >> 4) * 8];
        }
#pragma unroll
        for (int i = 0; i < 4; ++i)
#pragma unroll
            for (int j = 0; j < 4; ++j)
                acc[i][j] = __builtin_amdgcn_mfma_f32_16x16x32_bf16(
                    af[i], bfr[j], acc[i][j], 0, 0, 0);
    }

    const int row0 = bm + wr * 64, col0 = bn + wc * 64;
#pragma unroll
    for (int i = 0; i < 4; ++i) {
#pragma unroll
        for (int j = 0; j < 4; ++j) {
            const int n = col0 + j * 16 + (lane & 15);
            const int mb = row0 + i * 16 + ((lane >> 4) << 2);
            f32x4 v = acc[i][j];
            if constexpr (EPI == 0 || EPI == 1) {
                float bs = bias[n];
                unsigned short* o = (unsigned short*)out;
#pragma unroll
                for (int q = 0; q < 4; ++q) {
                    float val = v[q] + bs;
                    if constexpr (EPI == 0) val = val / (1.f + __expf(-val));
                    o[(size_t)(mb + q) * ldo + n] = f2bf(val);
                }
            } else if constexpr (EPI == 2) {
                float bs = bias[n];
                ushort4 pk;
                unsigned short* pku = (unsigned short*)&pk;
#pragma unroll
                for (int q = 0; q < 4; ++q) {
                    int m = mb + q;
                    float g = bf2f(gate[(size_t)m * ldg + n]);
                    float val = (v[q] + bs) / (1.f + __expf(-g));
                    pku[q] = f2bf(val);
                }
                // vT layout: [batch][D=1024][L=2048]; m = b*2048 + l
                unsigned short* o = (unsigned short*)out;
                size_t oi = ((size_t)(mb >> 11) * 1024 + n) * 2048 + (mb & 2047);
                *(ushort4*)(o + oi) = pk;
            } else if constexpr (EPI == 3) {
                float* o = (float*)out + (size_t)z * Obs;
#pragma unroll
                for (int q = 0; q < 4; ++q)
                    o[(size_t)(mb + q) * ldo + n] = v[q] * scale;
            } else {  // EPI == 4
                float* o = (float*)out + (size_t)z * Obs;
                const float* xr = xres + (size_t)z * Obs;
                float mw = mix[n];
#pragma unroll
                for (int q = 0; q < 4; ++q)
                    o[(size_t)(mb + q) * ldo + n] =
                        mw * v[q] + (1.f - mw) * xr[(size_t)(mb + q) * ldo + n];
            }
        }
    }
}

// ---------------- row softmax, f32 in -> bf16 out, IN PLACE (row-aliased) --
__global__ __launch_bounds__(256) void softmax_inplace(float* __restrict__ scores) {
    const int L = 2048;
    float* sr = scores + (size_t)blockIdx.x * L;
    const int t = threadIdx.x, lane = t & 63, wid = t >> 6;
    float4 a = ((const float4*)sr)[2 * t];
    float4 b = ((const float4*)sr)[2 * t + 1];
    float vv[8] = {a.x, a.y, a.z, a.w, b.x, b.y, b.z, b.w};
    float mx = vv[0];
#pragma unroll
    for (int i = 1; i < 8; ++i) mx = fmaxf(mx, vv[i]);
#pragma unroll
    for (int off = 32; off; off >>= 1) mx = fmaxf(mx, __shfl_xor(mx, off));
    __shared__ float redm[4], reds[4];
    if (lane == 0) redm[wid] = mx;
    __syncthreads();
    mx = fmaxf(fmaxf(redm[0], redm[1]), fmaxf(redm[2], redm[3]));
    float s = 0.f;
#pragma unroll
    for (int i = 0; i < 8; ++i) {
        vv[i] = __expf(vv[i] - mx);
        s += vv[i];
    }
#pragma unroll
    for (int off = 32; off; off >>= 1) s += __shfl_xor(s, off);
    if (lane == 0) reds[wid] = s;
    __syncthreads();
    s = reds[0] + reds[1] + reds[2] + reds[3];
    float inv = 1.f / s;
    ushort4 p0, p1;
    unsigned short* pp0 = (unsigned short*)&p0;
    unsigned short* pp1 = (unsigned short*)&p1;
#pragma unroll
    for (int i = 0; i < 4; ++i) pp0[i] = f2bf(vv[i] * inv);
#pragma unroll
    for (int i = 0; i < 4; ++i) pp1[i] = f2bf(vv[4 + i] * inv);
    unsigned short* pr = (unsigned short*)sr;  // bf16 P aliases row start
    ((ushort4*)pr)[2 * t] = p0;
    ((ushort4*)pr)[2 * t + 1] = p1;
}

// ---------------- in-place RMSNorm over rows of D=1024 f32 ----------------
__global__ __launch_bounds__(256) void rmsnorm_inplace(
    float* __restrict__ io, const float* __restrict__ w) {
    const int D = 1024;
    float* r = io + (size_t)blockIdx.x * D;
    const int t = threadIdx.x, lane = t & 63, wid = t >> 6;
    float4 v = ((const float4*)r)[t];
    float ss = v.x * v.x + v.y * v.y + v.z * v.z + v.w * v.w;
#pragma unroll
    for (int off = 32; off; off >>= 1) ss += __shfl_xor(ss, off);
    __shared__ float red[4];
    if (lane == 0) red[wid] = ss;
    __syncthreads();
    ss = red[0] + red[1] + red[2] + red[3];
    float sc = rsqrtf(ss / (float)D + 1e-6f);
    float4 wv = ((const float4*)w)[t];
    v.x *= sc * wv.x; v.y *= sc * wv.y; v.z *= sc * wv.z; v.w *= sc * wv.w;
    ((float4*)r)[t] = v;
}

// ---------------------------------------------------------------------------
extern "C" void kernel_launch(void* const* d_in, const int* in_sizes, int n_in,
                              void* d_out, int out_size, void* d_ws, size_t ws_size,
                              hipStream_t stream) {
    const float* x = (const float*)d_in[0];
    const float* W1 = (const float*)d_in[1];
    const float* b1 = (const float*)d_in[2];
    const float* W2 = (const float*)d_in[3];
    const float* b2 = (const float*)d_in[4];
    const float* Wv = (const float*)d_in[5];
    const float* bv = (const float*)d_in[6];
    const float* mixw = (const float*)d_in[7];
    const float* normw = (const float*)d_in[8];
    float* out = (float*)d_out;

    const int L = 2048, D = 1024, INNER = 1536, BN = 4;
    const int M = BN * L;  // 8192

    // workspace carve (~191 MB total)
    char* w = (char*)d_ws;
    auto carve = [&](size_t bytes) {
        void* p = (void*)w;
        w += (bytes + 255) & ~(size_t)255;
        return p;
    };
    unsigned short* xbf = (unsigned short*)carve((size_t)M * D * 2);
    unsigned short* w1t = (unsigned short*)carve((size_t)INNER * D * 2);
    unsigned short* w2t = (unsigned short*)carve((size_t)3 * D * INNER * 2);
    unsigned short* wvt = (unsigned short*)carve((size_t)D * D * 2);
    unsigned short* h = (unsigned short*)carve((size_t)M * INNER * 2);
    unsigned short* qkg = (unsigned short*)carve((size_t)M * 3 * D * 2);
    unsigned short* vt = (unsigned short*)carve((size_t)BN * D * L * 2);
    float* scores = (float*)carve((size_t)BN * L * L * 4);

    // 1) x -> bf16
    cvt_f32_bf16<<<(M * D) / 2048, 256, 0, stream>>>(x, xbf, (long long)M * D / 8);
    // 2-4) weights -> bf16, transposed to [N][K]
    transpose_cvt<<<dim3(INNER / 32, D / 32), 256, 0, stream>>>(W1, w1t, D, INNER);
    transpose_cvt<<<dim3(3 * D / 32, INNER / 32), 256, 0, stream>>>(W2, w2t, INNER, 3 * D);
    transpose_cvt<<<dim3(D / 32, D / 32), 256, 0, stream>>>(Wv, wvt, D, D);
    // 5) h = silu(x @ W1 + b1)           [M][INNER] bf16
    gemm_bt<0><<<dim3(INNER / 128, M / 128, 1), 256, 0, stream>>>(
        xbf, D, 0, w1t, D, 0, D, h, INNER, 0, b1, nullptr, 0, nullptr, nullptr, 1.f);
    // 6) qkg = h @ W2 + b2               [M][3D] bf16
    gemm_bt<1><<<dim3(3 * D / 128, M / 128, 1), 256, 0, stream>>>(
        h, INNER, 0, w2t, INNER, 0, INNER, qkg, 3 * D, 0, b2, nullptr, 0, nullptr,
        nullptr, 1.f);
    // 7) vT = ((x @ Wv + bv) * sigmoid(g))^T  [B][D][L] bf16
    gemm_bt<2><<<dim3(D / 128, M / 128, 1), 256, 0, stream>>>(
        xbf, D, 0, wvt, D, 0, D, vt, L, 0, bv, qkg + 2 * D, 3 * D, nullptr, nullptr,
        1.f);
    // 8) scores = q @ k^T / 32           [B][L][L] f32
    gemm_bt<3><<<dim3(L / 128, L / 128, BN), 256, 0, stream>>>(
        qkg, 3 * D, (long long)L * 3 * D, qkg + D, 3 * D, (long long)L * 3 * D, D,
        scores, L, (long long)L * L, nullptr, nullptr, 0, nullptr, nullptr, 0.03125f);
    // 9) softmax rows, write bf16 P in place (row pitch 2L ushorts)
    softmax_inplace<<<BN * L, 256, 0, stream>>>(scores);
    // 10) out = mix * (P @ vT^T) + (1-mix) * x    [B][L][D] f32
    gemm_bt<4><<<dim3(D / 128, L / 128, BN), 256, 0, stream>>>(
        (const unsigned short*)scores, 2 * L, (long long)L * 2 * L, vt, L,
        (long long)D * L, L, out, D, (long long)L * D, nullptr, nullptr, 0, x, mixw,
        1.f);
    // 11) in-place rmsnorm
    rmsnorm_inplace<<<M, 256, 0, stream>>>(out, normw);
}

// Round 2
// 310.972 us; speedup vs baseline: 1.2240x; 1.2240x over previous
//
#include <hip/hip_runtime.h>
#include <hip/hip_bf16.h>
#include <stdint.h>

// ---------------------------------------------------------------------------
// SelectiveMixing: x->W1->silu->W2->(q,k,g); v=(x@Wv+bv)*sig(g);
// attn=softmax(qk^T/sqrt(D)); out=rmsnorm(mix*attn@v + (1-mix)*x)
// B=4, L=2048, D=1024, INNER=1536. All matmuls bf16 MFMA, f32 accum.
// GEMM: 256x128 tile, BK=64, 8 waves, 3-buffer LDS ring, counted vmcnt(6),
// XOR-swizzled LDS (byte ^= (row&7)<<4) with pre-swizzled global source.
// ---------------------------------------------------------------------------

typedef __bf16 bf16x8 __attribute__((ext_vector_type(8)));
typedef float f32x4 __attribute__((ext_vector_type(4)));

__device__ __forceinline__ unsigned short f2bf(float f) {
    unsigned int u = __float_as_uint(f);
    u += 0x7fffu + ((u >> 16) & 1u);
    return (unsigned short)(u >> 16);
}
__device__ __forceinline__ float bf2f(unsigned short s) {
    return __uint_as_float(((unsigned int)s) << 16);
}
__device__ __forceinline__ void llds16(const void* g, void* l) {
    __builtin_amdgcn_global_load_lds(
        (const __attribute__((address_space(1))) void*)g,
        (__attribute__((address_space(3))) void*)l, 16, 0, 0);
}

// ---------------- elementwise: f32 -> bf16 (8 elems/thread) ----------------
__global__ __launch_bounds__(256) void cvt_f32_bf16(
    const float* __restrict__ in, unsigned short* __restrict__ out, long long n8) {
    long long i = (long long)blockIdx.x * 256 + threadIdx.x;
    if (i >= n8) return;
    float4 a = ((const float4*)in)[2 * i];
    float4 b = ((const float4*)in)[2 * i + 1];
    ushort4 p0, p1;
    p0.x = f2bf(a.x); p0.y = f2bf(a.y); p0.z = f2bf(a.z); p0.w = f2bf(a.w);
    p1.x = f2bf(b.x); p1.y = f2bf(b.y); p1.z = f2bf(b.z); p1.w = f2bf(b.w);
    ((ushort4*)out)[2 * i] = p0;
    ((ushort4*)out)[2 * i + 1] = p1;
}

// ---------------- transpose + convert: f32 [R][C] -> bf16 [C][R] -----------
__global__ __launch_bounds__(256) void transpose_cvt(
    const float* __restrict__ in, unsigned short* __restrict__ out, int R, int C) {
    __shared__ unsigned short tile[32][33];
    int c0 = blockIdx.x * 32, r0 = blockIdx.y * 32;
    int cc = threadIdx.x & 31, rr = threadIdx.x >> 5;
#pragma unroll
    for (int p = 0; p < 4; ++p) {
        int r = rr + p * 8;
        tile[r][cc] = f2bf(in[(size_t)(r0 + r) * C + c0 + cc]);
    }
    __syncthreads();
#pragma unroll
    for (int p = 0; p < 4; ++p) {
        int c = rr + p * 8;
        out[(size_t)(c0 + c) * R + r0 + cc] = tile[cc][c];
    }
}

// ---------------- pipelined bf16 GEMM, C = A @ B^T, templated epilogue -----
// A: [M][K] bf16 (row-major, lda), B: [N][K] bf16 (row-major, ldb)
// Tile 256(M) x 128(N) x 64(K). 512 threads = 8 waves (4 row x 2 col), each
// wave computes 64x64. LDS: 3 buffers x (A 32KB + B 16KB) = 144 KB ring.
// EPI 0: out bf16 = silu(acc + bias[n])
// EPI 1: out bf16 = acc + bias[n]
// EPI 2: vT bf16: out[(m>>11)*1024 + n][m&2047] = (acc+bias[n])*sigmoid(gate)
// EPI 3: out f32 = acc * scale
// EPI 4: out f32 = mix[n]*acc + (1-mix[n])*xres
template <int EPI>
__global__ __launch_bounds__(512, 1) void gemm3(
    const unsigned short* __restrict__ A, int lda, long long Abs,
    const unsigned short* __restrict__ B, int ldb, long long Bbs,
    int K,
    void* __restrict__ out, int ldo, long long Obs,
    const float* __restrict__ bias,
    const unsigned short* __restrict__ gate, int ldg,
    const float* __restrict__ xres, const float* __restrict__ mix,
    float scale) {
    extern __shared__ unsigned short lds[];
    constexpr int BUFU = 24576;  // ushorts per ring buffer (A 16384 + B 8192)
    const int tid = threadIdx.x;
    const int lane = tid & 63, wid = tid >> 6;
    const int wr = wid >> 1, wc = wid & 1;
    const int bm = blockIdx.y * 256, bn = blockIdx.x * 128;
    const int z = blockIdx.z;
    A += (long long)z * Abs;
    B += (long long)z * Bbs;
    const int NT = K >> 6;

    // --- staging: thread t covers linear LDS ushort offset chunk*4096 + t*8.
    // r = chunk-row, s = 16B slot; global col slot = s ^ (r&7) (pre-swizzle).
    const int sr = tid >> 3, ss = tid & 7;
    size_t ag[4], bg[2];
#pragma unroll
    for (int j = 0; j < 4; ++j) {
        int r = j * 64 + sr;
        ag[j] = (size_t)(bm + r) * lda + (size_t)((ss ^ (r & 7)) * 8);
    }
#pragma unroll
    for (int j = 0; j < 2; ++j) {
        int r = j * 64 + sr;
        bg[j] = (size_t)(bn + r) * ldb + (size_t)((ss ^ (r & 7)) * 8);
    }
    const int aL = wid * 512;  // wave-uniform LDS base within a 64-row chunk

    // --- fragment read offsets (row&7 == lane&7 since frag rows step by 16)
    const int arow = wr * 64 + (lane & 15);
    const int brow = wc * 64 + (lane & 15);
    const int g4 = lane >> 4;
    const int sx0 = ((g4 ^ (lane & 7)) * 8);        // k-slot 0 (k 0..31)
    const int sx1 = (((4 + g4) ^ (lane & 7)) * 8);  // k-slot 1 (k 32..63)

    f32x4 acc[4][4] = {};

    // prologue: stage tiles 0 and 1
#pragma unroll
    for (int j = 0; j < 4; ++j) llds16(A + ag[j], &lds[j * 4096 + aL]);
#pragma unroll
    for (int j = 0; j < 2; ++j) llds16(B + bg[j], &lds[16384 + j * 4096 + aL]);
#pragma unroll
    for (int j = 0; j < 4; ++j) llds16(A + ag[j] + 64, &lds[BUFU + j * 4096 + aL]);
#pragma unroll
    for (int j = 0; j < 2; ++j)
        llds16(B + bg[j] + 64, &lds[BUFU + 16384 + j * 4096 + aL]);
    asm volatile("s_waitcnt vmcnt(6)" ::: "memory");  // tile 0 landed
    __builtin_amdgcn_s_barrier();

    int bb = 0;
    for (int t = 0; t < NT; ++t) {
        const bool st = (t + 2 < NT);
        if (st) {
            // stage tile t+2 into the buffer vacated by tile t-1 (reads of
            // t-1 completed before the previous barrier -> race-free)
            const int tgt = (bb >= BUFU) ? bb - BUFU : bb + 2 * BUFU;
            const size_t k0 = (size_t)(t + 2) << 6;
#pragma unroll
            for (int j = 0; j < 4; ++j)
                llds16(A + ag[j] + k0, &lds[tgt + j * 4096 + aL]);
#pragma unroll
            for (int j = 0; j < 2; ++j)
                llds16(B + bg[j] + k0, &lds[tgt + 16384 + j * 4096 + aL]);
        }
        __builtin_amdgcn_sched_barrier(0);  // keep stage issue ahead of reads
        const unsigned short* Ab = &lds[bb];
        const unsigned short* Bb = &lds[bb + 16384];
        bf16x8 a0[4], a1[4], b0[4], b1[4];
#pragma unroll
        for (int i = 0; i < 4; ++i) {
            a0[i] = *(const bf16x8*)&Ab[(arow + i * 16) * 64 + sx0];
            a1[i] = *(const bf16x8*)&Ab[(arow + i * 16) * 64 + sx1];
            b0[i] = *(const bf16x8*)&Bb[(brow + i * 16) * 64 + sx0];
            b1[i] = *(const bf16x8*)&Bb[(brow + i * 16) * 64 + sx1];
        }
#pragma unroll
        for (int i = 0; i < 4; ++i)
#pragma unroll
            for (int j = 0; j < 4; ++j)
                acc[i][j] = __builtin_amdgcn_mfma_f32_16x16x32_bf16(
                    a0[i], b0[j], acc[i][j], 0, 0, 0);
#pragma unroll
        for (int i = 0; i < 4; ++i)
#pragma unroll
            for (int j = 0; j < 4; ++j)
                acc[i][j] = __builtin_amdgcn_mfma_f32_16x16x32_bf16(
                    a1[i], b1[j], acc[i][j], 0, 0, 0);
        // all this wave's ds_reads retired before anyone re-stages buf bb
        asm volatile("s_waitcnt lgkmcnt(0)" ::: "memory");
        if (st) asm volatile("s_waitcnt vmcnt(6)" ::: "memory");  // t+1 landed
        else    asm volatile("s_waitcnt vmcnt(0)" ::: "memory");
        __builtin_amdgcn_s_barrier();
        bb = (bb == 2 * BUFU) ? 0 : bb + BUFU;
    }

    const int row0 = bm + wr * 64, col0 = bn + wc * 64;
#pragma unroll
    for (int i = 0; i < 4; ++i) {
#pragma unroll
        for (int j = 0; j < 4; ++j) {
            const int n = col0 + j * 16 + (lane & 15);
            const int mb = row0 + i * 16 + ((lane >> 4) << 2);
            f32x4 v = acc[i][j];
            if constexpr (EPI == 0 || EPI == 1) {
                float bs = bias[n];
                unsigned short* o = (unsigned short*)out;
#pragma unroll
                for (int q = 0; q < 4; ++q) {
                    float val = v[q] + bs;
                    if constexpr (EPI == 0) val = val / (1.f + __expf(-val));
                    o[(size_t)(mb + q) * ldo + n] = f2bf(val);
                }
            } else if constexpr (EPI == 2) {
                float bs = bias[n];
                ushort4 pk;
                unsigned short* pku = (unsigned short*)&pk;
#pragma unroll
                for (int q = 0; q < 4; ++q) {
                    int m = mb + q;
                    float g = bf2f(gate[(size_t)m * ldg + n]);
                    float val = (v[q] + bs) / (1.f + __expf(-g));
                    pku[q] = f2bf(val);
                }
                unsigned short* o = (unsigned short*)out;
                size_t oi = ((size_t)(mb >> 11) * 1024 + n) * 2048 + (mb & 2047);
                *(ushort4*)(o + oi) = pk;
            } else if constexpr (EPI == 3) {
                float* o = (float*)out + (size_t)z * Obs;
#pragma unroll
                for (int q = 0; q < 4; ++q)
                    o[(size_t)(mb + q) * ldo + n] = v[q] * scale;
            } else {  // EPI == 4
                float* o = (float*)out + (size_t)z * Obs;
                const float* xr = xres + (size_t)z * Obs;
                float mw = mix[n];
#pragma unroll
                for (int q = 0; q < 4; ++q)
                    o[(size_t)(mb + q) * ldo + n] =
                        mw * v[q] + (1.f - mw) * xr[(size_t)(mb + q) * ldo + n];
            }
        }
    }
}

// ---------------- row softmax, f32 in -> bf16 out, IN PLACE (row-aliased) --
__global__ __launch_bounds__(256) void softmax_inplace(float* __restrict__ scores) {
    const int L = 2048;
    float* sr = scores + (size_t)blockIdx.x * L;
    const int t = threadIdx.x, lane = t & 63, wid = t >> 6;
    float4 a = ((const float4*)sr)[2 * t];
    float4 b = ((const float4*)sr)[2 * t + 1];
    float vv[8] = {a.x, a.y, a.z, a.w, b.x, b.y, b.z, b.w};
    float mx = vv[0];
#pragma unroll
    for (int i = 1; i < 8; ++i) mx = fmaxf(mx, vv[i]);
#pragma unroll
    for (int off = 32; off; off >>= 1) mx = fmaxf(mx, __shfl_xor(mx, off));
    __shared__ float redm[4], reds[4];
    if (lane == 0) redm[wid] = mx;
    __syncthreads();
    mx = fmaxf(fmaxf(redm[0], redm[1]), fmaxf(redm[2], redm[3]));
    float s = 0.f;
#pragma unroll
    for (int i = 0; i < 8; ++i) {
        vv[i] = __expf(vv[i] - mx);
        s += vv[i];
    }
#pragma unroll
    for (int off = 32; off; off >>= 1) s += __shfl_xor(s, off);
    if (lane == 0) reds[wid] = s;
    __syncthreads();
    s = reds[0] + reds[1] + reds[2] + reds[3];
    float inv = 1.f / s;
    ushort4 p0, p1;
    unsigned short* pp0 = (unsigned short*)&p0;
    unsigned short* pp1 = (unsigned short*)&p1;
#pragma unroll
    for (int i = 0; i < 4; ++i) pp0[i] = f2bf(vv[i] * inv);
#pragma unroll
    for (int i = 0; i < 4; ++i) pp1[i] = f2bf(vv[4 + i] * inv);
    unsigned short* pr = (unsigned short*)sr;
    ((ushort4*)pr)[2 * t] = p0;
    ((ushort4*)pr)[2 * t + 1] = p1;
}

// ---------------- in-place RMSNorm over rows of D=1024 f32 ----------------
__global__ __launch_bounds__(256) void rmsnorm_inplace(
    float* __restrict__ io, const float* __restrict__ w) {
    const int D = 1024;
    float* r = io + (size_t)blockIdx.x * D;
    const int t = threadIdx.x, lane = t & 63, wid = t >> 6;
    float4 v = ((const float4*)r)[t];
    float ss = v.x * v.x + v.y * v.y + v.z * v.z + v.w * v.w;
#pragma unroll
    for (int off = 32; off; off >>= 1) ss += __shfl_xor(ss, off);
    __shared__ float red[4];
    if (lane == 0) red[wid] = ss;
    __syncthreads();
    ss = red[0] + red[1] + red[2] + red[3];
    float sc = rsqrtf(ss / (float)D + 1e-6f);
    float4 wv = ((const float4*)w)[t];
    v.x *= sc * wv.x; v.y *= sc * wv.y; v.z *= sc * wv.z; v.w *= sc * wv.w;
    ((float4*)r)[t] = v;
}

// ---------------------------------------------------------------------------
extern "C" void kernel_launch(void* const* d_in, const int* in_sizes, int n_in,
                              void* d_out, int out_size, void* d_ws, size_t ws_size,
                              hipStream_t stream) {
    const float* x = (const float*)d_in[0];
    const float* W1 = (const float*)d_in[1];
    const float* b1 = (const float*)d_in[2];
    const float* W2 = (const float*)d_in[3];
    const float* b2 = (const float*)d_in[4];
    const float* Wv = (const float*)d_in[5];
    const float* bv = (const float*)d_in[6];
    const float* mixw = (const float*)d_in[7];
    const float* normw = (const float*)d_in[8];
    float* out = (float*)d_out;

    const int L = 2048, D = 1024, INNER = 1536, BN4 = 4;
    const int M = BN4 * L;  // 8192
    const int SMEM = 147456;

    (void)hipFuncSetAttribute(reinterpret_cast<const void*>(&gemm3<0>),
                              hipFuncAttributeMaxDynamicSharedMemorySize, SMEM);
    (void)hipFuncSetAttribute(reinterpret_cast<const void*>(&gemm3<1>),
                              hipFuncAttributeMaxDynamicSharedMemorySize, SMEM);
    (void)hipFuncSetAttribute(reinterpret_cast<const void*>(&gemm3<2>),
                              hipFuncAttributeMaxDynamicSharedMemorySize, SMEM);
    (void)hipFuncSetAttribute(reinterpret_cast<const void*>(&gemm3<3>),
                              hipFuncAttributeMaxDynamicSharedMemorySize, SMEM);
    (void)hipFuncSetAttribute(reinterpret_cast<const void*>(&gemm3<4>),
                              hipFuncAttributeMaxDynamicSharedMemorySize, SMEM);

    // workspace carve (~191 MB total)
    char* w = (char*)d_ws;
    auto carve = [&](size_t bytes) {
        void* p = (void*)w;
        w += (bytes + 255) & ~(size_t)255;
        return p;
    };
    unsigned short* xbf = (unsigned short*)carve((size_t)M * D * 2);
    unsigned short* w1t = (unsigned short*)carve((size_t)INNER * D * 2);
    unsigned short* w2t = (unsigned short*)carve((size_t)3 * D * INNER * 2);
    unsigned short* wvt = (unsigned short*)carve((size_t)D * D * 2);
    unsigned short* h = (unsigned short*)carve((size_t)M * INNER * 2);
    unsigned short* qkg = (unsigned short*)carve((size_t)M * 3 * D * 2);
    unsigned short* vt = (unsigned short*)carve((size_t)BN4 * D * L * 2);
    float* scores = (float*)carve((size_t)BN4 * L * L * 4);

    // 1) x -> bf16
    cvt_f32_bf16<<<(M * D) / 2048, 256, 0, stream>>>(x, xbf, (long long)M * D / 8);
    // 2-4) weights -> bf16, transposed to [N][K]
    transpose_cvt<<<dim3(INNER / 32, D / 32), 256, 0, stream>>>(W1, w1t, D, INNER);
    transpose_cvt<<<dim3(3 * D / 32, INNER / 32), 256, 0, stream>>>(W2, w2t, INNER, 3 * D);
    transpose_cvt<<<dim3(D / 32, D / 32), 256, 0, stream>>>(Wv, wvt, D, D);
    // 5) h = silu(x @ W1 + b1)           [M][INNER] bf16
    gemm3<0><<<dim3(INNER / 128, M / 256, 1), 512, SMEM, stream>>>(
        xbf, D, 0, w1t, D, 0, D, h, INNER, 0, b1, nullptr, 0, nullptr, nullptr, 1.f);
    // 6) qkg = h @ W2 + b2               [M][3D] bf16
    gemm3<1><<<dim3(3 * D / 128, M / 256, 1), 512, SMEM, stream>>>(
        h, INNER, 0, w2t, INNER, 0, INNER, qkg, 3 * D, 0, b2, nullptr, 0, nullptr,
        nullptr, 1.f);
    // 7) vT = ((x @ Wv + bv) * sigmoid(g))^T  [B][D][L] bf16
    gemm3<2><<<dim3(D / 128, M / 256, 1), 512, SMEM, stream>>>(
        xbf, D, 0, wvt, D, 0, D, vt, L, 0, bv, qkg + 2 * D, 3 * D, nullptr, nullptr,
        1.f);
    // 8) scores = q @ k^T / 32           [B][L][L] f32
    gemm3<3><<<dim3(L / 128, L / 256, BN4), 512, SMEM, stream>>>(
        qkg, 3 * D, (long long)L * 3 * D, qkg + D, 3 * D, (long long)L * 3 * D, D,
        scores, L, (long long)L * L, nullptr, nullptr, 0, nullptr, nullptr, 0.03125f);
    // 9) softmax rows, write bf16 P in place (row pitch 2L ushorts)
    softmax_inplace<<<BN4 * L, 256, 0, stream>>>(scores);
    // 10) out = mix * (P @ vT^T) + (1-mix) * x    [B][L][D] f32
    gemm3<4><<<dim3(D / 128, L / 256, BN4), 512, SMEM, stream>>>(
        (const unsigned short*)scores, 2 * L, (long long)L * 2 * L, vt, L,
        (long long)D * L, L, out, D, (long long)L * D, nullptr, nullptr, 0, x, mixw,
        1.f);
    // 11) in-place rmsnorm
    rmsnorm_inplace<<<M, 256, 0, stream>>>(out, normw);
}